// Round 17
// baseline (45.759 us; speedup 1.0000x reference)
//
#include <hip/hip_runtime.h>

// LVAE_shGLM encoder, fused bf16-MFMA implementation for gfx950.
// Round 17: pipe-overlap levers on the r11 base (best: 40.5us dispatch).
// Ledger of falsified walls: TLP(flat), MFMA-count(flat), rounds(flat),
// LDS-traffic(flat), co-residency depth 3(flat). Compute floor = 25.6GF /
// 2495TF = 10.3us = measured MfmaUtil*dur -> the gap is pipe non-overlap.
// This round: (1) T5 s_setprio(1) around MFMA clusters (2 blocks/CU at
// decorrelated phases -> scheduler can favor MFMA waves); (2) mu_mid GEMM
// fused INTO the GEMM3 kt loop (independent MFMA+loads under the same
// latency window, kills the serial 4b phase); unroll 2 on GEMM3 to hold
// the 128-reg cap (r15-proven).
//
//   h_mid  = relu(windows @ W1 + b1)   windows[t,k] = pad[t+k]
//   mu_mid = h_mid @ W2 + b2           -> out[:, 0:4]
//   h_leaf = relu(h_mid @ Wl1 + bl1)
//   mu_leaf= h_leaf @ Wl2 + bl2        -> out[:, 4:20]

typedef __bf16 bf16;
typedef __bf16 bf16x8 __attribute__((ext_vector_type(8)));
typedef float  f32x4  __attribute__((ext_vector_type(4)));
typedef float  f32x16 __attribute__((ext_vector_type(16)));

constexpr int T_DATA = 100000;
constexpr int T_V    = 100;
constexpr int WIN    = 199;   // 2*T_V - 1
constexpr int HID    = 256;
constexpr int BT     = 128;   // timesteps per block
constexpr int HSTR   = 264;   // h-buffer row stride (elems); 528B (16B-aligned)
constexpr int VLEN   = 352;   // window span: 128 rows + 207 max k + 8 frag + pad
constexpr int VSTR   = 360;   // Vdup row stride (720B, 16B-aligned)

// ws layout in bf16 elements (written by pack_weights), 1KB groups:
//   [0*512     ..) PW1_32   13 kt(K=16) x 8 nt(32 cols)  = 104 groups (k>=199 zeroed)
//   [104*512   ..) PWL1_32  16 kt x 8 nt                 = 128 groups
//   [232*512   ..) PW2      8 kt(K=32), 16x16 frag, cols 0..3 real
//   [240*512   ..) PWL2     8 kt(K=32), 16x16 frag, 16 cols
constexpr int PWL1_OFF = 104 * 512;
constexpr int PW2_OFF  = 232 * 512;
constexpr int PWL2_OFF = 240 * 512;   // total 248 KB <= ws

__global__ void pack_weights(const float* __restrict__ W1, const float* __restrict__ W2,
                             const float* __restrict__ Wl1, const float* __restrict__ Wl2,
                             bf16* __restrict__ ws) {
  const int gid  = blockIdx.x * blockDim.x + threadIdx.x;  // [0, 15872)
  const int lane = gid & 63;
  const int grp  = gid >> 6;        // [0, 248)
  bf16x8 v;
  if (grp < 104) {                  // PW1_32: 32x32x16 B frag: col=lane&31, k=(lane>>5)*8+j
    const int kt = grp >> 3, nt = grp & 7, n = nt * 32 + (lane & 31);
#pragma unroll
    for (int j = 0; j < 8; ++j) {
      const int k = kt * 16 + (lane >> 5) * 8 + j;
      v[j] = (k < WIN) ? (bf16)W1[k * HID + n] : (bf16)0.0f;
    }
  } else if (grp < 232) {           // PWL1_32
    const int q = grp - 104;
    const int kt = q >> 3, nt = q & 7, n = nt * 32 + (lane & 31);
#pragma unroll
    for (int j = 0; j < 8; ++j) {
      const int k = kt * 16 + (lane >> 5) * 8 + j;
      v[j] = (bf16)Wl1[k * HID + n];
    }
  } else if (grp < 240) {           // PW2: 16x16x32 frag: col=lane&15, k=(lane>>4)*8+j
    const int kt = grp - 232, m = lane & 15;
#pragma unroll
    for (int j = 0; j < 8; ++j) {
      const int k = kt * 32 + (lane >> 4) * 8 + j;
      v[j] = (m < 4) ? (bf16)W2[k * 4 + m] : (bf16)0.0f;
    }
  } else {                          // PWL2
    const int kt = grp - 240, m = lane & 15;
#pragma unroll
    for (int j = 0; j < 8; ++j) {
      const int k = kt * 32 + (lane >> 4) * 8 + j;
      v[j] = (bf16)Wl2[k * 16 + m];
    }
  }
  *reinterpret_cast<bf16x8*>(ws + (size_t)gid * 8) = v;
}

__global__ __launch_bounds__(512, 4) void fused_enc(
    const float* __restrict__ V, const float* __restrict__ b1,
    const float* __restrict__ b2, const float* __restrict__ bl1,
    const float* __restrict__ bl2, const bf16* __restrict__ ws,
    float* __restrict__ out) {
  __shared__ bf16 Vdup[8][VSTR];    // 5.8 KB: Vdup[p][q] = pad[t0-99+q+p]
  __shared__ bf16 hbuf[BT * HSTR];  // 67.6 KB: h_mid, then h_leaf (WAR barrier)
  // total 73344 B -> 2 blocks/CU

  const int tid  = threadIdx.x;
  const int lane = tid & 63;
  const int w    = tid >> 6;            // wave id [0,8): owns 32-col stripe w
  const int c5   = lane & 31;           // 32x32 frag col/row index
  const int hi   = lane >> 5;           // 32x32 frag k-half
  const int m    = lane & 15;           // 16x16 frag index
  const int g    = lane >> 4;           // 16x16 k-group
  const long t0  = (long)blockIdx.x * BT;

  // ---- 1. stage 8 shifted bf16 window copies ----
  for (int c = tid; c < 8 * VLEN; c += 512) {
    const int p = c / VLEN, q = c - p * VLEN;
    const long src = t0 + q + p - (T_V - 1);
    const float v = (src >= 0 && src < T_DATA) ? V[src] : 0.0f;
    Vdup[p][q] = (bf16)v;
  }
  __syncthreads();   // B0

  // A-frag element s = (rt*32 + c5) + kt*16 + hi*8 + j; s mod 8 = lane&7
  // (rt*32 is 0 mod 8) -> copy p = lane&7 gives one aligned b128 read.
  const int p  = lane & 7;
  const int qb = (c5 + hi * 8) - p;     // aligned base within Vdup row p
  const bf16* vrow = &Vdup[p][0];

  f32x16 acc[4];                        // row-tiles rt: rows rt*32 .. rt*32+31
#pragma unroll
  for (int rt = 0; rt < 4; ++rt) acc[rt] = (f32x16){};

  // ---- 2. GEMM1: h_mid(pre) = windows @ W1, 13 kt of K=16 ----
#pragma unroll
  for (int kt = 0; kt < 13; ++kt) {
    const bf16x8 b = *reinterpret_cast<const bf16x8*>(
        ws + (size_t)(kt * 8 + w) * 512 + lane * 8);
    bf16x8 a[4];
#pragma unroll
    for (int rt = 0; rt < 4; ++rt)
      a[rt] = *reinterpret_cast<const bf16x8*>(vrow + qb + kt * 16 + rt * 32);
    __builtin_amdgcn_s_setprio(1);
#pragma unroll
    for (int rt = 0; rt < 4; ++rt)
      acc[rt] = __builtin_amdgcn_mfma_f32_32x32x16_bf16(a[rt], b, acc[rt], 0, 0, 0);
    __builtin_amdgcn_s_setprio(0);
  }

  // ---- 3. h_mid epilogue: bias+relu -> hbuf ----
  // C/D 32x32 layout: col = lane&31, row = rt*32 + (r&3) + 8*(r>>2) + 4*(lane>>5)
  const int   col = w * 32 + c5;
  const float bb1 = b1[col];
#pragma unroll
  for (int rt = 0; rt < 4; ++rt)
#pragma unroll
    for (int r = 0; r < 16; ++r) {
      const int row = rt * 32 + (r & 3) + 8 * (r >> 2) + 4 * hi;
      hbuf[row * HSTR + col] = (bf16)fmaxf(acc[rt][r] + bb1, 0.0f);
    }
  __syncthreads();   // B1: h_mid visible

  // ---- 4. GEMM3 (+fused mu_mid): h_leaf(pre) = h_mid @ Wl1, 16 kt of K=16 ----
  // mu_mid rides inside the loop: independent MFMA + loads under the same
  // latency window. Wave w owns output rows w*16..w*16+15 for mu.
#pragma unroll
  for (int rt = 0; rt < 4; ++rt) acc[rt] = (f32x16){};
  f32x4 mu = {0.f, 0.f, 0.f, 0.f};
#pragma unroll 2
  for (int kt = 0; kt < 16; ++kt) {
    const bf16x8 b = *reinterpret_cast<const bf16x8*>(
        ws + PWL1_OFF + (size_t)(kt * 8 + w) * 512 + lane * 8);
    const int koff = kt * 16 + hi * 8;
    bf16x8 a[4];
#pragma unroll
    for (int rt = 0; rt < 4; ++rt)
      a[rt] = *reinterpret_cast<const bf16x8*>(&hbuf[(rt * 32 + c5) * HSTR + koff]);
    __builtin_amdgcn_s_setprio(1);
#pragma unroll
    for (int rt = 0; rt < 4; ++rt)
      acc[rt] = __builtin_amdgcn_mfma_f32_32x32x16_bf16(a[rt], b, acc[rt], 0, 0, 0);
    __builtin_amdgcn_s_setprio(0);
    if ((kt & 1) == 0) {   // one mu2 MFMA per K=32 (two kt of K=16)
      const bf16x8 amu = *reinterpret_cast<const bf16x8*>(
          &hbuf[(w * 16 + m) * HSTR + (kt >> 1) * 32 + g * 8]);
      const bf16x8 bw2 = *reinterpret_cast<const bf16x8*>(
          ws + PW2_OFF + (size_t)(kt >> 1) * 512 + lane * 8);
      mu = __builtin_amdgcn_mfma_f32_16x16x32_bf16(amu, bw2, mu, 0, 0, 0);
    }
  }
  {
    const float b2v = (m < 4) ? b2[m] : 0.0f;
#pragma unroll
    for (int j = 0; j < 4; ++j) {       // C 16x16: col=lane&15, row=(lane>>4)*4+reg
      const long t = t0 + w * 16 + g * 4 + j;
      if (t < T_DATA && m < 4) out[t * 20 + m] = mu[j] + b2v;
    }
  }
  __syncthreads();   // B2 (WAR): all h_mid reads done before h_leaf overwrite

  // ---- 5. h_leaf epilogue: bias+relu -> hbuf ----
  const float bbl = bl1[col];
#pragma unroll
  for (int rt = 0; rt < 4; ++rt)
#pragma unroll
    for (int r = 0; r < 16; ++r) {
      const int row = rt * 32 + (r & 3) + 8 * (r >> 2) + 4 * hi;
      hbuf[row * HSTR + col] = (bf16)fmaxf(acc[rt][r] + bbl, 0.0f);
    }
  __syncthreads();   // B3: h_leaf visible

  // ---- 6. mu_leaf: wave w handles rows w*16 .. w*16+15 ----
  mu = (f32x4){0.f, 0.f, 0.f, 0.f};
#pragma unroll
  for (int kq = 0; kq < 8; ++kq) {
    const bf16x8 a = *reinterpret_cast<const bf16x8*>(
        &hbuf[(w * 16 + m) * HSTR + kq * 32 + g * 8]);
    const bf16x8 b = *reinterpret_cast<const bf16x8*>(
        ws + PWL2_OFF + (size_t)kq * 512 + lane * 8);
    mu = __builtin_amdgcn_mfma_f32_16x16x32_bf16(a, b, mu, 0, 0, 0);
  }
  {
    const float blv = bl2[m];
#pragma unroll
    for (int j = 0; j < 4; ++j) {
      const long t = t0 + w * 16 + g * 4 + j;
      if (t < T_DATA) out[t * 20 + 4 + m] = mu[j] + blv;
    }
  }
}

extern "C" void kernel_launch(void* const* d_in, const int* in_sizes, int n_in,
                              void* d_out, int out_size, void* d_ws, size_t ws_size,
                              hipStream_t stream) {
  const float* V   = (const float*)d_in[0];
  const float* W1  = (const float*)d_in[1];
  const float* b1  = (const float*)d_in[2];
  const float* W2  = (const float*)d_in[3];
  const float* b2  = (const float*)d_in[4];
  const float* Wl1 = (const float*)d_in[5];
  const float* bl1 = (const float*)d_in[6];
  const float* Wl2 = (const float*)d_in[7];
  const float* bl2 = (const float*)d_in[8];
  bf16* ws = (bf16*)d_ws;   // needs 253952 bytes
  float* out = (float*)d_out;

  pack_weights<<<62, 256, 0, stream>>>(W1, W2, Wl1, Wl2, ws);

  const int grid = (T_DATA + BT - 1) / BT;   // 782
  fused_enc<<<grid, 512, 0, stream>>>(V, b1, b2, bl1, bl2, ws, out);
}

// Round 18
// 40.235 us; speedup vs baseline: 1.1373x; 1.1373x over previous
//
#include <hip/hip_runtime.h>

// LVAE_shGLM encoder, fused bf16-MFMA implementation for gfx950.
// Round 18: transposed compute. All prior levers flat; the untouched term is
// the epilogue/store issue stream (128 scalar ds_write_b16 + stride-20 scalar
// global stores per wave). Swap MFMA operands: D = W^T * X^T with prepacked
// weights as the A operand (A/B frag layouts mirror; pack_weights and Vdup
// are byte-identical to r11's verified versions). D's lane now owns a fixed
// timestep and 4-consecutive-channel groups -> epilogue = 16 packed
// ds_write_b64 (was 64 scalar b16), hbuf = [t][channel] (reads stay b128
// contiguous), mu outputs = one dwordx4 global store per lane.
//
//   h_mid  = relu(windows @ W1 + b1)   windows[t,k] = pad[t+k]
//   mu_mid = h_mid @ W2 + b2           -> out[:, 0:4]
//   h_leaf = relu(h_mid @ Wl1 + bl1)
//   mu_leaf= h_leaf @ Wl2 + bl2        -> out[:, 4:20]

typedef __bf16 bf16;
typedef __bf16 bf16x8 __attribute__((ext_vector_type(8)));
typedef __bf16 bf16x4 __attribute__((ext_vector_type(4)));
typedef float  f32x4  __attribute__((ext_vector_type(4)));
typedef float  f32x16 __attribute__((ext_vector_type(16)));

constexpr int T_DATA = 100000;
constexpr int T_V    = 100;
constexpr int WIN    = 199;   // 2*T_V - 1
constexpr int HID    = 256;
constexpr int BT     = 128;   // timesteps per block
constexpr int CSTR   = 264;   // hbuf row stride: [t][channel], 528B (16B-aligned)
constexpr int VLEN   = 352;   // window span: 128 t + 207 max k + 8 frag + pad
constexpr int VSTR   = 360;   // Vdup row stride (720B, 16B-aligned)

// ws layout in bf16 elements (identical to r10-r17, byte-for-byte):
//   [0*512     ..) PW1   13 kt(K=16) x 8 mt(32 ch) = 104 groups (k>=199 zeroed)
//   [104*512   ..) PWL1  16 kt x 8 mt              = 128 groups
//   [232*512   ..) PW2   8 kt(K=32), 16x16 frag, ch 0..3 real
//   [240*512   ..) PWL2  8 kt(K=32), 16x16 frag, 16 ch
// Reinterpretation: these groups are now the A-operand (W^T) fragments —
// A-frag lane layout mirrors B-frag, so the stored bytes serve both.
constexpr int PWL1_OFF = 104 * 512;
constexpr int PW2_OFF  = 232 * 512;
constexpr int PWL2_OFF = 240 * 512;   // total 248 KB <= ws

__global__ void pack_weights(const float* __restrict__ W1, const float* __restrict__ W2,
                             const float* __restrict__ Wl1, const float* __restrict__ Wl2,
                             bf16* __restrict__ ws) {
  const int gid  = blockIdx.x * blockDim.x + threadIdx.x;  // [0, 15872)
  const int lane = gid & 63;
  const int grp  = gid >> 6;        // [0, 248)
  bf16x8 v;
  if (grp < 104) {                  // PW1: lane(row)=ch, k=(lane>>5)*8+j
    const int kt = grp >> 3, nt = grp & 7, n = nt * 32 + (lane & 31);
#pragma unroll
    for (int j = 0; j < 8; ++j) {
      const int k = kt * 16 + (lane >> 5) * 8 + j;
      v[j] = (k < WIN) ? (bf16)W1[k * HID + n] : (bf16)0.0f;
    }
  } else if (grp < 232) {           // PWL1
    const int q = grp - 104;
    const int kt = q >> 3, nt = q & 7, n = nt * 32 + (lane & 31);
#pragma unroll
    for (int j = 0; j < 8; ++j) {
      const int k = kt * 16 + (lane >> 5) * 8 + j;
      v[j] = (bf16)Wl1[k * HID + n];
    }
  } else if (grp < 240) {           // PW2: 16x16 frag, ch 0..3 real
    const int kt = grp - 232, m = lane & 15;
#pragma unroll
    for (int j = 0; j < 8; ++j) {
      const int k = kt * 32 + (lane >> 4) * 8 + j;
      v[j] = (m < 4) ? (bf16)W2[k * 4 + m] : (bf16)0.0f;
    }
  } else {                          // PWL2
    const int kt = grp - 240, m = lane & 15;
#pragma unroll
    for (int j = 0; j < 8; ++j) {
      const int k = kt * 32 + (lane >> 4) * 8 + j;
      v[j] = (bf16)Wl2[k * 16 + m];
    }
  }
  *reinterpret_cast<bf16x8*>(ws + (size_t)gid * 8) = v;
}

__global__ __launch_bounds__(512, 4) void fused_enc(
    const float* __restrict__ V, const float* __restrict__ b1,
    const float* __restrict__ b2, const float* __restrict__ bl1,
    const float* __restrict__ bl2, const bf16* __restrict__ ws,
    float* __restrict__ out) {
  __shared__ bf16 Vdup[8][VSTR];    // 5.8 KB: Vdup[p][q] = pad[t0-99+q+p]
  __shared__ bf16 hbuf[BT * CSTR];  // 67.6 KB: H = h^T as [t][channel]
  // total 73344 B -> 2 blocks/CU

  const int tid  = threadIdx.x;
  const int lane = tid & 63;
  const int w    = tid >> 6;            // wave id [0,8): owns 32-channel stripe w
  const int c5   = lane & 31;           // 32x32 frag row/col index
  const int hi   = lane >> 5;           // 32x32 frag k-half
  const int m    = lane & 15;           // 16x16 frag index
  const int g    = lane >> 4;           // 16x16 k-group
  const long t0  = (long)blockIdx.x * BT;

  // ---- 1. stage 8 shifted bf16 window copies (unchanged from r11) ----
  for (int c = tid; c < 8 * VLEN; c += 512) {
    const int p = c / VLEN, q = c - p * VLEN;
    const long src = t0 + q + p - (T_V - 1);
    const float v = (src >= 0 && src < T_DATA) ? V[src] : 0.0f;
    Vdup[p][q] = (bf16)v;
  }
  __syncthreads();   // B0

  // B-frag (windows as B): element s = (nt*32 + c5) + kt*16 + hi*8 + j;
  // s mod 8 = c5&7 = lane&7 (lane-constant) -> copy p gives one aligned b128.
  const int p  = lane & 7;
  const int qb = (c5 + hi * 8) - p;     // multiple of 8; 16B-aligned base
  const bf16* vrow = &Vdup[p][0];

  f32x16 acc[4];                        // [nt]: t-tiles nt*32..nt*32+31, ch stripe w
#pragma unroll
  for (int nt = 0; nt < 4; ++nt) acc[nt] = (f32x16){};

  // ---- 2. GEMM1: H1[ch][t] = W1^T (A, global prepack) x windows^T (B, LDS) ----
#pragma unroll
  for (int kt = 0; kt < 13; ++kt) {
    const bf16x8 a = *reinterpret_cast<const bf16x8*>(
        ws + (size_t)(kt * 8 + w) * 512 + lane * 8);
#pragma unroll
    for (int nt = 0; nt < 4; ++nt) {
      const bf16x8 b = *reinterpret_cast<const bf16x8*>(vrow + qb + nt * 32 + kt * 16);
      acc[nt] = __builtin_amdgcn_mfma_f32_32x32x16_bf16(a, b, acc[nt], 0, 0, 0);
    }
  }

  // ---- 3. h_mid epilogue: packed b64 writes. D: col=t (c5), row=channel =
  //      (r&3) + 8*(r>>2) + 4*hi -> r=4q+i covers 4 consecutive channels. ----
  {
    f32x4 bb[4];
#pragma unroll
    for (int q = 0; q < 4; ++q)
      bb[q] = *reinterpret_cast<const f32x4*>(&b1[w * 32 + 8 * q + 4 * hi]);
#pragma unroll
    for (int nt = 0; nt < 4; ++nt) {
      const int t = nt * 32 + c5;
#pragma unroll
      for (int q = 0; q < 4; ++q) {
        bf16x4 hv;
#pragma unroll
        for (int i = 0; i < 4; ++i)
          hv[i] = (bf16)fmaxf(acc[nt][4 * q + i] + bb[q][i], 0.0f);
        *reinterpret_cast<bf16x4*>(&hbuf[t * CSTR + w * 32 + 8 * q + 4 * hi]) = hv;
      }
    }
  }
  __syncthreads();   // B1: h_mid visible

  // ---- 4. GEMM3: H2 = Wl1^T x H1 (B-frag: 8 contiguous channels at fixed t) ----
#pragma unroll
  for (int nt = 0; nt < 4; ++nt) acc[nt] = (f32x16){};
#pragma unroll
  for (int kt = 0; kt < 16; ++kt) {
    const bf16x8 a = *reinterpret_cast<const bf16x8*>(
        ws + PWL1_OFF + (size_t)(kt * 8 + w) * 512 + lane * 8);
    const int koff = kt * 16 + hi * 8;
#pragma unroll
    for (int nt = 0; nt < 4; ++nt) {
      const bf16x8 b = *reinterpret_cast<const bf16x8*>(
          &hbuf[(nt * 32 + c5) * CSTR + koff]);
      acc[nt] = __builtin_amdgcn_mfma_f32_32x32x16_bf16(a, b, acc[nt], 0, 0, 0);
    }
  }

  // ---- 4b. mu_mid = W2^T x H1: wave w owns t-tile w (t = w*16 + m) ----
  f32x4 mu = {0.f, 0.f, 0.f, 0.f};
#pragma unroll
  for (int kt = 0; kt < 8; ++kt) {
    const bf16x8 a = *reinterpret_cast<const bf16x8*>(
        ws + PW2_OFF + (size_t)kt * 512 + lane * 8);
    const bf16x8 b = *reinterpret_cast<const bf16x8*>(
        &hbuf[(w * 16 + m) * CSTR + kt * 32 + g * 8]);
    mu = __builtin_amdgcn_mfma_f32_16x16x32_bf16(a, b, mu, 0, 0, 0);
  }
  {
    // D: col=t (m), row=channel g*4+j -> lanes g==0 hold channels 0..3.
    const long t = t0 + w * 16 + m;
    if (g == 0 && t < T_DATA) {
      const f32x4 b2v = *reinterpret_cast<const f32x4*>(b2);
      f32x4 o;
#pragma unroll
      for (int j = 0; j < 4; ++j) o[j] = mu[j] + b2v[j];
      *reinterpret_cast<f32x4*>(&out[t * 20]) = o;   // one dwordx4 store
    }
  }
  __syncthreads();   // B2 (WAR): all h_mid reads done before h_leaf overwrite

  // ---- 5. h_leaf epilogue: packed b64 writes ----
  {
    f32x4 bb[4];
#pragma unroll
    for (int q = 0; q < 4; ++q)
      bb[q] = *reinterpret_cast<const f32x4*>(&bl1[w * 32 + 8 * q + 4 * hi]);
#pragma unroll
    for (int nt = 0; nt < 4; ++nt) {
      const int t = nt * 32 + c5;
#pragma unroll
      for (int q = 0; q < 4; ++q) {
        bf16x4 hv;
#pragma unroll
        for (int i = 0; i < 4; ++i)
          hv[i] = (bf16)fmaxf(acc[nt][4 * q + i] + bb[q][i], 0.0f);
        *reinterpret_cast<bf16x4*>(&hbuf[t * CSTR + w * 32 + 8 * q + 4 * hi]) = hv;
      }
    }
  }
  __syncthreads();   // B3: h_leaf visible

  // ---- 6. mu_leaf = Wl2^T x H2: one dwordx4 store per lane ----
  mu = (f32x4){0.f, 0.f, 0.f, 0.f};
#pragma unroll
  for (int kq = 0; kq < 8; ++kq) {
    const bf16x8 a = *reinterpret_cast<const bf16x8*>(
        ws + PWL2_OFF + (size_t)kq * 512 + lane * 8);
    const bf16x8 b = *reinterpret_cast<const bf16x8*>(
        &hbuf[(w * 16 + m) * CSTR + kq * 32 + g * 8]);
    mu = __builtin_amdgcn_mfma_f32_16x16x32_bf16(a, b, mu, 0, 0, 0);
  }
  {
    const long t = t0 + w * 16 + m;
    if (t < T_DATA) {
      const f32x4 blv = *reinterpret_cast<const f32x4*>(&bl2[g * 4]);
      f32x4 o;
#pragma unroll
      for (int j = 0; j < 4; ++j) o[j] = mu[j] + blv[j];
      *reinterpret_cast<f32x4*>(&out[t * 20 + 4 + g * 4]) = o;  // 16B-aligned
    }
  }
}

extern "C" void kernel_launch(void* const* d_in, const int* in_sizes, int n_in,
                              void* d_out, int out_size, void* d_ws, size_t ws_size,
                              hipStream_t stream) {
  const float* V   = (const float*)d_in[0];
  const float* W1  = (const float*)d_in[1];
  const float* b1  = (const float*)d_in[2];
  const float* W2  = (const float*)d_in[3];
  const float* b2  = (const float*)d_in[4];
  const float* Wl1 = (const float*)d_in[5];
  const float* bl1 = (const float*)d_in[6];
  const float* Wl2 = (const float*)d_in[7];
  const float* bl2 = (const float*)d_in[8];
  bf16* ws = (bf16*)d_ws;   // needs 253952 bytes
  float* out = (float*)d_out;

  pack_weights<<<62, 256, 0, stream>>>(W1, W2, Wl1, Wl2, ws);

  const int grid = (T_DATA + BT - 1) / BT;   // 782
  fused_enc<<<grid, 512, 0, stream>>>(V, b1, b2, bl1, bl2, ws, out);
}